// Round 1
// baseline (209.353 us; speedup 1.0000x reference)
//
#include <hip/hip_runtime.h>

// Problem geometry (fixed by setup_inputs): B=4, C=96 (F=32 lights x 3), H=W=256.
// img/light are NCHW fp32: element (b, c, h, w) at ((b*96 + c) * 65536 + h*256 + w).
// Channel c maps to light f = c/3, component = c%3 (NHWC reshape (F,3)).
// Output: (4, 3, 256, 256) fp32.

constexpr int FLIGHTS = 32;
constexpr int QROW    = 16384;   // 65536 pixels / 4 per float4
constexpr int CH      = 96;

__device__ __forceinline__ float fc(const float4 v, int j) {
    return j == 0 ? v.x : j == 1 ? v.y : j == 2 ? v.z : v.w;
}
__device__ __forceinline__ void setc(float4& v, int j, float x) {
    if (j == 0) v.x = x; else if (j == 1) v.y = x; else if (j == 2) v.z = x; else v.w = x;
}

__global__ __launch_bounds__(256) void LS_44160853737780_kernel(
    const float4* __restrict__ img,
    const float4* __restrict__ light,
    float4* __restrict__ out)
{
    int q = blockIdx.x * blockDim.x + threadIdx.x;  // quad index in [0, 4*16384)
    int b = q >> 14;            // batch
    int p = q & 16383;          // float4-column within the image plane

    const float4* ib = img   + (size_t)(b * CH) * QROW + p;
    const float4* lb = light + (size_t)(b * CH) * QROW + p;

    // Per-pixel (j = 0..3) accumulators: symmetric LtL (6) + LtI (3).
    float A00[4] = {0,0,0,0}, A01[4] = {0,0,0,0}, A02[4] = {0,0,0,0},
          A11[4] = {0,0,0,0}, A12[4] = {0,0,0,0}, A22[4] = {0,0,0,0},
          r0[4]  = {0,0,0,0}, r1[4]  = {0,0,0,0}, r2[4]  = {0,0,0,0};

    #pragma unroll 4
    for (int f = 0; f < FLIGHTS; ++f) {
        float4 ix = ib[(3 * f + 0) * QROW];
        float4 iy = ib[(3 * f + 1) * QROW];
        float4 iz = ib[(3 * f + 2) * QROW];
        float4 lx = lb[(3 * f + 0) * QROW];
        float4 ly = lb[(3 * f + 1) * QROW];
        float4 lz = lb[(3 * f + 2) * QROW];
        #pragma unroll
        for (int j = 0; j < 4; ++j) {
            float x = fc(ix, j), y = fc(iy, j), z = fc(iz, j);
            float I = sqrtf(x * x + y * y + z * z);     // per-light intensity
            float a = fc(lx, j), c = fc(ly, j), d = fc(lz, j);
            A00[j] += a * a; A01[j] += a * c; A02[j] += a * d;
            A11[j] += c * c; A12[j] += c * d; A22[j] += d * d;
            r0[j]  += a * I; r1[j]  += c * I; r2[j]  += d * I;
        }
    }

    float4 o0, o1, o2;
    #pragma unroll
    for (int j = 0; j < 4; ++j) {
        float a00 = A00[j], a01 = A01[j], a02 = A02[j],
              a11 = A11[j], a12 = A12[j], a22 = A22[j];
        // Adjugate of symmetric 3x3 (also symmetric).
        float c00 = a11 * a22 - a12 * a12;
        float c01 = a02 * a12 - a01 * a22;
        float c02 = a01 * a12 - a02 * a11;
        float c11 = a00 * a22 - a02 * a02;
        float c12 = a01 * a02 - a00 * a12;
        float c22 = a00 * a11 - a01 * a01;
        float det = a00 * c00 + a01 * c01 + a02 * c02;
        float inv = 1.0f / det;   // SPD (32 random outer products) => det > 0
        float n0 = (c00 * r0[j] + c01 * r1[j] + c02 * r2[j]) * inv;
        float n1 = (c01 * r0[j] + c11 * r1[j] + c12 * r2[j]) * inv;
        float n2 = (c02 * r0[j] + c12 * r1[j] + c22 * r2[j]) * inv;
        float nn = sqrtf(n0 * n0 + n1 * n1 + n2 * n2);
        float s  = 1.0f / (nn + 1e-10f);
        setc(o0, j, n0 * s);
        setc(o1, j, n1 * s);
        setc(o2, j, n2 * s);
    }

    float4* ob = out + (size_t)(b * 3) * QROW + p;
    ob[0]        = o0;
    ob[QROW]     = o1;
    ob[2 * QROW] = o2;
}

extern "C" void kernel_launch(void* const* d_in, const int* in_sizes, int n_in,
                              void* d_out, int out_size, void* d_ws, size_t ws_size,
                              hipStream_t stream) {
    const float4* img   = (const float4*)d_in[0];
    const float4* light = (const float4*)d_in[1];
    float4* out = (float4*)d_out;
    // 4 batches * 16384 quads = 65536 threads; 256 threads/block -> 256 blocks.
    LS_44160853737780_kernel<<<dim3(256), dim3(256), 0, stream>>>(img, light, out);
}